// Round 8
// baseline (654.350 us; speedup 1.0000x reference)
//
#include <hip/hip_runtime.h>
#include <hip/hip_bf16.h>
#include <float.h>

// Problem constants
constexpr int kB = 2, kS = 2048, kSE = 2048, kL = 4096, kHID = 768, kH = 12, kD = 64;

typedef __attribute__((ext_vector_type(8))) short bfrag;   // 8 bf16 (4 VGPRs)
typedef __attribute__((ext_vector_type(4))) float f32x4;   // 4 fp32 acc

// RNE float->bf16 via compiler-lowered cvt (m240: don't hand-write cvt_pk)
__device__ __forceinline__ short f2bf(float x) {
  __hip_bfloat16 h = __float2bfloat16(x);
  short s;
  __builtin_memcpy(&s, &h, 2);
  return s;
}

// softmax uses exp2; fold 1/sqrt(64) * log2(e) into Q at LN time
#define QSCALE (0.125f * 1.44269504088896340736f)

// ---------------------------------------------------------------------------
// Kernel 1: LayerNorm (q and kv) + copy encoder_output into bf16 ekv buffer.
// mode 0: LN(q) -> q_hs (f32, residual) + qbf (bf16, PRE-SCALED by QSCALE)
// mode 1: LN(kv) -> ekv_bf[:, SE+s, :]
// mode 2: enc -> ekv_bf[:, s, :]
// ---------------------------------------------------------------------------
__global__ __launch_bounds__(256) void ln_copy_kernel(
    const float* __restrict__ qin, const float* __restrict__ kvin,
    const float* __restrict__ enc, const float* __restrict__ g,
    const float* __restrict__ beta, float* __restrict__ q_hs,
    short* __restrict__ ekv, short* __restrict__ qbf)
{
  const int row = blockIdx.x;            // b*2048 + s
  const int mode = blockIdx.y;
  const int t = threadIdx.x;
  const int b = row >> 11, s = row & 2047;

  if (mode == 2) {
    const float4* src = (const float4*)(enc + (size_t)row * kHID);
    short* dst = ekv + ((size_t)b * kL + s) * kHID;
    if (t < 192) {
      float4 v = src[t];
      short4 o = {f2bf(v.x), f2bf(v.y), f2bf(v.z), f2bf(v.w)};
      *(short4*)(dst + t * 4) = o;
    }
    return;
  }

  const float* x = (mode == 0 ? qin : kvin) + (size_t)row * kHID;
  float v0 = x[t], v1 = x[t + 256], v2 = x[t + 512];
  float sum = v0 + v1 + v2;
  float sq  = v0 * v0 + v1 * v1 + v2 * v2;
  #pragma unroll
  for (int off = 32; off > 0; off >>= 1) {
    sum += __shfl_down(sum, off, 64);
    sq  += __shfl_down(sq,  off, 64);
  }
  __shared__ float red[8];
  const int wave = t >> 6;
  if ((t & 63) == 0) { red[wave] = sum; red[wave + 4] = sq; }
  __syncthreads();
  const float tsum = red[0] + red[1] + red[2] + red[3];
  const float tsq  = red[4] + red[5] + red[6] + red[7];
  const float mu   = tsum * (1.0f / kHID);
  const float var  = tsq * (1.0f / kHID) - mu * mu;
  const float rstd = rsqrtf(var + 1e-12f);

  const float o0 = (v0 - mu) * rstd * g[t]       + beta[t];
  const float o1 = (v1 - mu) * rstd * g[t + 256] + beta[t + 256];
  const float o2 = (v2 - mu) * rstd * g[t + 512] + beta[t + 512];

  if (mode == 0) {
    float* out = q_hs + (size_t)row * kHID;
    out[t] = o0; out[t + 256] = o1; out[t + 512] = o2;
    short* ob = qbf + (size_t)row * kHID;
    ob[t]       = f2bf(o0 * QSCALE);
    ob[t + 256] = f2bf(o1 * QSCALE);
    ob[t + 512] = f2bf(o2 * QSCALE);
  } else {
    short* out = ekv + ((size_t)b * kL + kSE + s) * kHID;
    out[t] = f2bf(o0); out[t + 256] = f2bf(o1); out[t + 512] = f2bf(o2);
  }
}

// ---------------------------------------------------------------------------
// Kernel 1b: pack (am & dm & ~eye) into bit-mask words [B][S][32] u64.
// ---------------------------------------------------------------------------
__global__ __launch_bounds__(64) void mask_pack_kernel(
    const unsigned char* __restrict__ am, const unsigned char* __restrict__ dm,
    unsigned long long* __restrict__ pmask)
{
  const int row = blockIdx.x;            // b*2048 + s
  const int b = row >> 11, s = row & 2047;
  const int lane = threadIdx.x;
  const unsigned char* dmr = dm + (size_t)row * kS;
  const unsigned char* amr = am + (size_t)b * kS;
  #pragma unroll 4
  for (int w = 0; w < 32; w++) {
    const int le = w * 64 + lane;
    const bool v = amr[le] && dmr[le] && (s != le);
    const unsigned long long word = __ballot(v);
    if (lane == 0) pmask[(size_t)row * 32 + w] = word;
  }
}

// ---------------------------------------------------------------------------
// Kernel 1c: convert Wkv and dense_w to bf16 (one shot).
// ---------------------------------------------------------------------------
__global__ __launch_bounds__(256) void cvt_w_kernel(
    const float* __restrict__ w1, const float* __restrict__ w2,
    short* __restrict__ o1, short* __restrict__ o2)
{
  const int n1 = 2 * kHID * kHID;
  const int n2 = kHID * kHID;
  const int tot = (n1 + n2) / 4;
  for (int idx = blockIdx.x * 256 + threadIdx.x; idx < tot; idx += gridDim.x * 256) {
    const int i4 = idx * 4;
    if (i4 < n1) {
      float4 v = *(const float4*)(w1 + i4);
      short4 o = {f2bf(v.x), f2bf(v.y), f2bf(v.z), f2bf(v.w)};
      *(short4*)(o1 + i4) = o;
    } else {
      float4 v = *(const float4*)(w2 + (i4 - n1));
      short4 o = {f2bf(v.x), f2bf(v.y), f2bf(v.z), f2bf(v.w)};
      *(short4*)(o2 + (i4 - n1)) = o;
    }
  }
}

// ---------------------------------------------------------------------------
// Kernel 2: bf16 MFMA GEMM. 128x128 tile, BK=64, 4 waves (2x2), 4x4 frags.
// MODE 0: merged KV projection, grid (64,12); n0<768 -> K epilogue
//         [B,H,L,D]; n0>=768 -> V (swapped operands) -> V^T [B,H,D,L].
// MODE 1: dense + bias + resid -> fp32 out, grid (32,6).
// ---------------------------------------------------------------------------
template <int MODE>
__global__ __launch_bounds__(256) void gemm_mfma(
    const short* __restrict__ A, const short* __restrict__ W,
    const float* __restrict__ bias, short* __restrict__ kb,
    short* __restrict__ vt, float* __restrict__ outf,
    const float* __restrict__ resid)
{
  __shared__ short As[128 * 64];
  __shared__ short Bs[128 * 64];
  const int t = threadIdx.x;
  const int m0 = blockIdx.x * 128;
  const int n0 = blockIdx.y * 128;
  const bool isV = (MODE == 0) && (n0 >= kHID);
  const int wv = t >> 6, lane = t & 63;
  const int g = lane >> 4, ln = lane & 15;
  const int wr = wv >> 1, wc = wv & 1;

  f32x4 acc[4][4] = {};   // K/dense: [i=m][j=n]; V: [i=n][j=m]

  for (int kt = 0; kt < kHID; kt += 64) {
    uint4 ra[4], rb[4];
    #pragma unroll
    for (int r = 0; r < 4; r++) {
      const int f = t + r * 256;
      const int row = f >> 3, c = f & 7;
      ra[r] = *(const uint4*)(A + (size_t)(m0 + row) * kHID + kt + c * 8);
      rb[r] = *(const uint4*)(W + (size_t)(n0 + row) * kHID + kt + c * 8);
    }
    __syncthreads();
    #pragma unroll
    for (int r = 0; r < 4; r++) {
      const int f = t + r * 256;
      const int row = f >> 3, c = f & 7;
      const int sc = c ^ (row & 7);
      *(uint4*)&As[row * 64 + sc * 8] = ra[r];
      *(uint4*)&Bs[row * 64 + sc * 8] = rb[r];
    }
    __syncthreads();

    bfrag a0[4], a1[4], b0[4], b1[4];
    #pragma unroll
    for (int i = 0; i < 4; i++) {
      const int ar = wr * 64 + i * 16 + ln;
      a0[i] = *(const bfrag*)&As[ar * 64 + (((g + 0) ^ (ln & 7)) << 3)];
      a1[i] = *(const bfrag*)&As[ar * 64 + (((g + 4) ^ (ln & 7)) << 3)];
      const int br = wc * 64 + i * 16 + ln;
      b0[i] = *(const bfrag*)&Bs[br * 64 + (((g + 0) ^ (ln & 7)) << 3)];
      b1[i] = *(const bfrag*)&Bs[br * 64 + (((g + 4) ^ (ln & 7)) << 3)];
    }
    if (isV) {
      #pragma unroll
      for (int i = 0; i < 4; i++)
        #pragma unroll
        for (int j = 0; j < 4; j++) {
          acc[i][j] = __builtin_amdgcn_mfma_f32_16x16x32_bf16(b0[i], a0[j], acc[i][j], 0, 0, 0);
          acc[i][j] = __builtin_amdgcn_mfma_f32_16x16x32_bf16(b1[i], a1[j], acc[i][j], 0, 0, 0);
        }
    } else {
      #pragma unroll
      for (int i = 0; i < 4; i++)
        #pragma unroll
        for (int j = 0; j < 4; j++) {
          acc[i][j] = __builtin_amdgcn_mfma_f32_16x16x32_bf16(a0[i], b0[j], acc[i][j], 0, 0, 0);
          acc[i][j] = __builtin_amdgcn_mfma_f32_16x16x32_bf16(a1[i], b1[j], acc[i][j], 0, 0, 0);
        }
    }
  }

  // C/D layout (m89): col = lane&15, row = (lane>>4)*4 + reg
  if (MODE == 0 && !isV) {
    #pragma unroll
    for (int j = 0; j < 4; j++) {
      const int n = n0 + wc * 64 + j * 16 + ln;       // < 768
      const float bn = bias[n];
      const int h = n >> 6, d = n & 63;
      #pragma unroll
      for (int i = 0; i < 4; i++)
        #pragma unroll
        for (int r = 0; r < 4; r++) {
          const int m = m0 + wr * 64 + i * 16 + g * 4 + r;
          kb[(((size_t)((m >> 12) * kH + h)) * kL + (m & 4095)) * kD + d] =
              f2bf(acc[i][j][r] + bn);
        }
    }
  } else if (MODE == 0) {
    #pragma unroll
    for (int i = 0; i < 4; i++)
      #pragma unroll
      for (int r = 0; r < 4; r++) {
        const int n = n0 + wc * 64 + i * 16 + g * 4 + r;   // >= 768
        const float bn = bias[n];
        const int nn = n - kHID;
        const int h = nn >> 6, d = nn & 63;
        #pragma unroll
        for (int j = 0; j < 4; j++) {
          const int m = m0 + wr * 64 + j * 16 + ln;
          vt[(((size_t)((m >> 12) * kH + h)) * kD + d) * kL + (m & 4095)] =
              f2bf(acc[i][j][r] + bn);
        }
      }
  } else {
    #pragma unroll
    for (int j = 0; j < 4; j++) {
      const int n = n0 + wc * 64 + j * 16 + ln;
      const float bn = bias[n];
      #pragma unroll
      for (int i = 0; i < 4; i++)
        #pragma unroll
        for (int r = 0; r < 4; r++) {
          const int m = m0 + wr * 64 + i * 16 + g * 4 + r;
          const size_t off = (size_t)m * kHID + n;
          outf[off] = acc[i][j][r] + bn + resid[off];
        }
    }
  }
}

// ---------------------------------------------------------------------------
// Kernel 3: barrier-free flash attention, MFMA 16x16x32 bf16.
// grid (S/64, H, B), 256 thr = 4 independent waves (16 q-rows each).
// Swapped QK^T: accS = mfma(K, Q) -> lane owns q = lane&15; l = nt*16+g*4+r.
// K and V^T fragments are read DIRECTLY from global (no LDS, no barriers).
// Softmax: 2-shuffle row reduce (xor 16,32); exp2 domain (scale pre-folded
// into Q); zero-threshold defer-max. P staged in per-wave LDS (2 KB) as the
// PV A-operand, chunk-XOR-swizzled exactly like the verified R3/R5 pattern.
// ---------------------------------------------------------------------------
__global__ __launch_bounds__(256, 3) void attn_mfma(
    const short* __restrict__ qbf, const short* __restrict__ kbuf,
    const short* __restrict__ vtbuf, const unsigned long long* __restrict__ pmask,
    short* __restrict__ attn_out)
{
  __shared__ short Ps[4][16 * 64];

  const int qt = blockIdx.x, h = blockIdx.y, b = blockIdx.z;
  const int s0 = qt * 64;
  const int t = threadIdx.x;
  const int wv = t >> 6, lane = t & 63;
  const int g = lane >> 4, ln = lane & 15;

  const short* Kg = kbuf + ((size_t)(b * kH + h)) * kL * kD;
  const short* Vg = vtbuf + ((size_t)(b * kH + h)) * kD * kL;

  // Q (B-operand): lane holds col q = ln, k-chunks g / g+4. Pre-scaled.
  const short* qrow = qbf + ((size_t)(b * kS + s0 + wv * 16 + ln)) * kHID + h * kD;
  const bfrag bQ0 = *(const bfrag*)(qrow + g * 8);
  const bfrag bQ1 = *(const bfrag*)(qrow + 32 + g * 8);

  const unsigned long long* pmrow =
      pmask + ((size_t)(b * kS + s0 + wv * 16 + ln)) * 32;

  short* myPs = &Ps[wv][0];
  const int rdP0 = ln * 64 + (((g + 0) ^ (ln & 7)) << 3);
  const int rdP1 = ln * 64 + (((g + 4) ^ (ln & 7)) << 3);

  f32x4 accO[4] = {};
  float mrun = -FLT_MAX, lrun = 0.f;
  const f32x4 zero = {0.f, 0.f, 0.f, 0.f};

  for (int lt = 0; lt < kL / 64; lt++) {
    // K fragments (A-operand): row l = lt*64 + nt*16 + ln, k-chunks g / g+4
    bfrag aK0[4], aK1[4], bV0[4], bV1[4];
    #pragma unroll
    for (int nt = 0; nt < 4; nt++) {
      const short* kp = Kg + (size_t)(lt * 64 + nt * 16 + ln) * kD;
      aK0[nt] = *(const bfrag*)(kp + g * 8);
      aK1[nt] = *(const bfrag*)(kp + 32 + g * 8);
    }
    // V^T fragments (B-operand): col d = nt*16 + ln, k (=l) chunks g / g+4
    #pragma unroll
    for (int nt = 0; nt < 4; nt++) {
      const short* vp = Vg + (size_t)(nt * 16 + ln) * kL + lt * 64;
      bV0[nt] = *(const bfrag*)(vp + g * 8);
      bV1[nt] = *(const bfrag*)(vp + 32 + g * 8);
    }

    // ---- S^T = K·Q^T : D[l][q], lane col q=ln, row l = nt*16 + g*4 + r ----
    f32x4 accS[4];
    #pragma unroll
    for (int nt = 0; nt < 4; nt++) {
      accS[nt] = __builtin_amdgcn_mfma_f32_16x16x32_bf16(aK0[nt], bQ0, zero, 0, 0, 0);
      accS[nt] = __builtin_amdgcn_mfma_f32_16x16x32_bf16(aK1[nt], bQ1, accS[nt], 0, 0, 0);
    }

    // ---- mask (decoder half): bit index l = nt*16 + g*4 + r ----
    if (lt >= kSE / 64) {
      const unsigned long long wm = pmrow[lt - kSE / 64];
      #pragma unroll
      for (int nt = 0; nt < 4; nt++) {
        const unsigned nib = (unsigned)(wm >> (nt * 16 + g * 4)) & 0xFu;
        #pragma unroll
        for (int r = 0; r < 4; r++)
          if (!((nib >> r) & 1u)) accS[nt][r] = -FLT_MAX;
      }
    }

    // ---- row max: 16 local + 2 shuffles (lanes xor 16, 32 share q-row) ----
    float pmax = accS[0][0];
    #pragma unroll
    for (int nt = 0; nt < 4; nt++)
      #pragma unroll
      for (int r = 0; r < 4; r++) pmax = fmaxf(pmax, accS[nt][r]);
    pmax = fmaxf(pmax, __shfl_xor(pmax, 16, 64));
    pmax = fmaxf(pmax, __shfl_xor(pmax, 32, 64));

    // ---- defer-max (threshold 0: mathematically exact) ----
    if (!__all(pmax <= mrun)) {
      const float mn = fmaxf(mrun, pmax);
      const float corr = exp2f(mrun - mn);
      mrun = mn;
      lrun *= corr;
      float c4[4];
      #pragma unroll
      for (int r = 0; r < 4; r++) c4[r] = __shfl(corr, g * 4 + r, 64);
      #pragma unroll
      for (int nt = 0; nt < 4; nt++) {
        accO[nt][0] *= c4[0]; accO[nt][1] *= c4[1];
        accO[nt][2] *= c4[2]; accO[nt][3] *= c4[3];
      }
    }

    // ---- P = 2^(S - m), row sum ----
    float ps = 0.f;
    #pragma unroll
    for (int nt = 0; nt < 4; nt++)
      #pragma unroll
      for (int r = 0; r < 4; r++) {
        const float p = exp2f(accS[nt][r] - mrun);
        accS[nt][r] = p;
        ps += p;
      }
    ps += __shfl_xor(ps, 16, 64);
    ps += __shfl_xor(ps, 32, 64);
    lrun += ps;

    // ---- pack P (bf16) into per-wave LDS, chunk-swizzled ----
    #pragma unroll
    for (int nt = 0; nt < 4; nt++) {
      short4 p4 = {f2bf(accS[nt][0]), f2bf(accS[nt][1]),
                   f2bf(accS[nt][2]), f2bf(accS[nt][3])};
      const int chunk = nt * 2 + (g >> 1);            // (nt*16+g*4) >> 3
      const int sc = chunk ^ (ln & 7);
      *(short4*)&myPs[ln * 64 + sc * 8 + (g & 1) * 4] = p4;
    }

    // ---- PV: O[q][d] += P·V (A = P row q=ln, B = V^T col d) ----
    const bfrag aP0 = *(const bfrag*)&myPs[rdP0];
    const bfrag aP1 = *(const bfrag*)&myPs[rdP1];
    #pragma unroll
    for (int nt = 0; nt < 4; nt++) {
      accO[nt] = __builtin_amdgcn_mfma_f32_16x16x32_bf16(aP0, bV0[nt], accO[nt], 0, 0, 0);
      accO[nt] = __builtin_amdgcn_mfma_f32_16x16x32_bf16(aP1, bV1[nt], accO[nt], 0, 0, 0);
    }
  }

  // ---- normalize + store: row q = g*4+r, col d = nt*16+ln ----
  const float linv = 1.0f / lrun;
  float i4[4];
  #pragma unroll
  for (int r = 0; r < 4; r++) i4[r] = __shfl(linv, g * 4 + r, 64);
  #pragma unroll
  for (int nt = 0; nt < 4; nt++)
    #pragma unroll
    for (int r = 0; r < 4; r++) {
      const int q = s0 + wv * 16 + g * 4 + r;
      attn_out[((size_t)(b * kS + q)) * kHID + h * kD + nt * 16 + ln] =
          f2bf(accO[nt][r] * i4[r]);
    }
}

// ---------------------------------------------------------------------------
extern "C" void kernel_launch(void* const* d_in, const int* in_sizes, int n_in,
                              void* d_out, int out_size, void* d_ws, size_t ws_size,
                              hipStream_t stream) {
  const float* q_in    = (const float*)d_in[0];
  const float* kv_in   = (const float*)d_in[1];
  const float* enc     = (const float*)d_in[2];
  const unsigned char* am = (const unsigned char*)d_in[3];
  const unsigned char* dm = (const unsigned char*)d_in[4];
  // d_in[5], d_in[6]: Wq (computed-then-discarded in reference) -> skipped
  const float* wkv_w   = (const float*)d_in[7];
  const float* wkv_b   = (const float*)d_in[8];
  const float* dense_w = (const float*)d_in[9];
  const float* dense_b = (const float*)d_in[10];
  const float* norm_g  = (const float*)d_in[11];
  const float* norm_b  = (const float*)d_in[12];
  float* out = (float*)d_out;

  float* ws = (float*)d_ws;
  float* q_hs   = ws;                                 // f32 [B,S,HID]   3,145,728 f
  short* ekv    = (short*)(ws + 3145728);             // bf16 [B,L,HID]  (3,145,728 f)
  short* kbuf   = (short*)(ws + 6291456);             // bf16 [B,H,L,D]  (3,145,728 f)
  short* vtbuf  = (short*)(ws + 9437184);             // bf16 [B,H,D,L]  (3,145,728 f)
  short* qbf    = (short*)(ws + 12582912);            // bf16 [B,S,HID]  (1,572,864 f)
  unsigned long long* pmask = (unsigned long long*)(ws + 14155776); // [B,S,32] u64
  short* wkv_bf = (short*)(ws + 14417920);            // bf16 [1536,768] (589,824 f)
  short* wd_bf  = (short*)(ws + 15007744);            // bf16 [768,768]  (294,912 f)
  short* attn_bf = ekv;                               // alias: ekv dead after KV GEMM

  hipLaunchKernelGGL(ln_copy_kernel, dim3(kB * kS, 3), dim3(256), 0, stream,
                     q_in, kv_in, enc, norm_g, norm_b, q_hs, ekv, qbf);
  hipLaunchKernelGGL(mask_pack_kernel, dim3(kB * kS), dim3(64), 0, stream,
                     am, dm, pmask);
  hipLaunchKernelGGL(cvt_w_kernel, dim3(1024), dim3(256), 0, stream,
                     wkv_w, dense_w, wkv_bf, wd_bf);
  hipLaunchKernelGGL((gemm_mfma<0>), dim3(64, 12), dim3(256), 0, stream,
                     ekv, wkv_bf, wkv_b, kbuf, vtbuf, nullptr, nullptr);
  hipLaunchKernelGGL(attn_mfma, dim3(kS / 64, kH, kB), dim3(256), 0, stream,
                     qbf, kbuf, vtbuf, pmask, attn_bf);
  hipLaunchKernelGGL((gemm_mfma<1>), dim3(32, 6), dim3(256), 0, stream,
                     attn_bf, wd_bf, dense_b, nullptr, nullptr, out, q_hs);
}

// Round 9
// 429.760 us; speedup vs baseline: 1.5226x; 1.5226x over previous
//
#include <hip/hip_runtime.h>
#include <hip/hip_bf16.h>
#include <float.h>

// Problem constants
constexpr int kB = 2, kS = 2048, kSE = 2048, kL = 4096, kHID = 768, kH = 12, kD = 64;

typedef __attribute__((ext_vector_type(8))) short bfrag;   // 8 bf16 (4 VGPRs)
typedef __attribute__((ext_vector_type(4))) float f32x4;   // 4 fp32 acc

// RNE float->bf16 via compiler-lowered cvt (m240: don't hand-write cvt_pk)
__device__ __forceinline__ short f2bf(float x) {
  __hip_bfloat16 h = __float2bfloat16(x);
  short s;
  __builtin_memcpy(&s, &h, 2);
  return s;
}

// softmax uses exp2; fold 1/sqrt(64) * log2(e) into Q at LN time
#define QSCALE (0.125f * 1.44269504088896340736f)

// ---------------------------------------------------------------------------
// Kernel 1: LayerNorm (q and kv) + copy encoder_output into bf16 ekv buffer.
// mode 0: LN(q) -> q_hs (f32, residual) + qbf (bf16, PRE-SCALED by QSCALE)
// mode 1: LN(kv) -> ekv_bf[:, SE+s, :]
// mode 2: enc -> ekv_bf[:, s, :]
// ---------------------------------------------------------------------------
__global__ __launch_bounds__(256) void ln_copy_kernel(
    const float* __restrict__ qin, const float* __restrict__ kvin,
    const float* __restrict__ enc, const float* __restrict__ g,
    const float* __restrict__ beta, float* __restrict__ q_hs,
    short* __restrict__ ekv, short* __restrict__ qbf)
{
  const int row = blockIdx.x;            // b*2048 + s
  const int mode = blockIdx.y;
  const int t = threadIdx.x;
  const int b = row >> 11, s = row & 2047;

  if (mode == 2) {
    const float4* src = (const float4*)(enc + (size_t)row * kHID);
    short* dst = ekv + ((size_t)b * kL + s) * kHID;
    if (t < 192) {
      float4 v = src[t];
      short4 o = {f2bf(v.x), f2bf(v.y), f2bf(v.z), f2bf(v.w)};
      *(short4*)(dst + t * 4) = o;
    }
    return;
  }

  const float* x = (mode == 0 ? qin : kvin) + (size_t)row * kHID;
  float v0 = x[t], v1 = x[t + 256], v2 = x[t + 512];
  float sum = v0 + v1 + v2;
  float sq  = v0 * v0 + v1 * v1 + v2 * v2;
  #pragma unroll
  for (int off = 32; off > 0; off >>= 1) {
    sum += __shfl_down(sum, off, 64);
    sq  += __shfl_down(sq,  off, 64);
  }
  __shared__ float red[8];
  const int wave = t >> 6;
  if ((t & 63) == 0) { red[wave] = sum; red[wave + 4] = sq; }
  __syncthreads();
  const float tsum = red[0] + red[1] + red[2] + red[3];
  const float tsq  = red[4] + red[5] + red[6] + red[7];
  const float mu   = tsum * (1.0f / kHID);
  const float var  = tsq * (1.0f / kHID) - mu * mu;
  const float rstd = rsqrtf(var + 1e-12f);

  const float o0 = (v0 - mu) * rstd * g[t]       + beta[t];
  const float o1 = (v1 - mu) * rstd * g[t + 256] + beta[t + 256];
  const float o2 = (v2 - mu) * rstd * g[t + 512] + beta[t + 512];

  if (mode == 0) {
    float* out = q_hs + (size_t)row * kHID;
    out[t] = o0; out[t + 256] = o1; out[t + 512] = o2;
    short* ob = qbf + (size_t)row * kHID;
    ob[t]       = f2bf(o0 * QSCALE);
    ob[t + 256] = f2bf(o1 * QSCALE);
    ob[t + 512] = f2bf(o2 * QSCALE);
  } else {
    short* out = ekv + ((size_t)b * kL + kSE + s) * kHID;
    out[t] = f2bf(o0); out[t + 256] = f2bf(o1); out[t + 512] = f2bf(o2);
  }
}

// ---------------------------------------------------------------------------
// Kernel 1b: pack (am & dm & ~eye) into bit-mask words [B][S][32] u64.
// ---------------------------------------------------------------------------
__global__ __launch_bounds__(64) void mask_pack_kernel(
    const unsigned char* __restrict__ am, const unsigned char* __restrict__ dm,
    unsigned long long* __restrict__ pmask)
{
  const int row = blockIdx.x;            // b*2048 + s
  const int b = row >> 11, s = row & 2047;
  const int lane = threadIdx.x;
  const unsigned char* dmr = dm + (size_t)row * kS;
  const unsigned char* amr = am + (size_t)b * kS;
  #pragma unroll 4
  for (int w = 0; w < 32; w++) {
    const int le = w * 64 + lane;
    const bool v = amr[le] && dmr[le] && (s != le);
    const unsigned long long word = __ballot(v);
    if (lane == 0) pmask[(size_t)row * 32 + w] = word;
  }
}

// ---------------------------------------------------------------------------
// Kernel 1c: convert Wkv and dense_w to bf16 (one shot).
// ---------------------------------------------------------------------------
__global__ __launch_bounds__(256) void cvt_w_kernel(
    const float* __restrict__ w1, const float* __restrict__ w2,
    short* __restrict__ o1, short* __restrict__ o2)
{
  const int n1 = 2 * kHID * kHID;
  const int n2 = kHID * kHID;
  const int tot = (n1 + n2) / 4;
  for (int idx = blockIdx.x * 256 + threadIdx.x; idx < tot; idx += gridDim.x * 256) {
    const int i4 = idx * 4;
    if (i4 < n1) {
      float4 v = *(const float4*)(w1 + i4);
      short4 o = {f2bf(v.x), f2bf(v.y), f2bf(v.z), f2bf(v.w)};
      *(short4*)(o1 + i4) = o;
    } else {
      float4 v = *(const float4*)(w2 + (i4 - n1));
      short4 o = {f2bf(v.x), f2bf(v.y), f2bf(v.z), f2bf(v.w)};
      *(short4*)(o2 + (i4 - n1)) = o;
    }
  }
}

// ---------------------------------------------------------------------------
// Kernel 2: bf16 MFMA GEMM. 128x128 tile, BK=64, 4 waves (2x2), 4x4 frags.
// MODE 0: merged KV projection, grid (64,12); n0<768 -> K epilogue
//         [B,H,L,D]; n0>=768 -> V (swapped operands) -> V^T [B,H,D,L].
// MODE 1: dense + bias + resid -> fp32 out, grid (32,6).
// ---------------------------------------------------------------------------
template <int MODE>
__global__ __launch_bounds__(256) void gemm_mfma(
    const short* __restrict__ A, const short* __restrict__ W,
    const float* __restrict__ bias, short* __restrict__ kb,
    short* __restrict__ vt, float* __restrict__ outf,
    const float* __restrict__ resid)
{
  __shared__ short As[128 * 64];
  __shared__ short Bs[128 * 64];
  const int t = threadIdx.x;
  const int m0 = blockIdx.x * 128;
  const int n0 = blockIdx.y * 128;
  const bool isV = (MODE == 0) && (n0 >= kHID);
  const int wv = t >> 6, lane = t & 63;
  const int g = lane >> 4, ln = lane & 15;
  const int wr = wv >> 1, wc = wv & 1;

  f32x4 acc[4][4] = {};   // K/dense: [i=m][j=n]; V: [i=n][j=m]

  for (int kt = 0; kt < kHID; kt += 64) {
    uint4 ra[4], rb[4];
    #pragma unroll
    for (int r = 0; r < 4; r++) {
      const int f = t + r * 256;
      const int row = f >> 3, c = f & 7;
      ra[r] = *(const uint4*)(A + (size_t)(m0 + row) * kHID + kt + c * 8);
      rb[r] = *(const uint4*)(W + (size_t)(n0 + row) * kHID + kt + c * 8);
    }
    __syncthreads();
    #pragma unroll
    for (int r = 0; r < 4; r++) {
      const int f = t + r * 256;
      const int row = f >> 3, c = f & 7;
      const int sc = c ^ (row & 7);
      *(uint4*)&As[row * 64 + sc * 8] = ra[r];
      *(uint4*)&Bs[row * 64 + sc * 8] = rb[r];
    }
    __syncthreads();

    bfrag a0[4], a1[4], b0[4], b1[4];
    #pragma unroll
    for (int i = 0; i < 4; i++) {
      const int ar = wr * 64 + i * 16 + ln;
      a0[i] = *(const bfrag*)&As[ar * 64 + (((g + 0) ^ (ln & 7)) << 3)];
      a1[i] = *(const bfrag*)&As[ar * 64 + (((g + 4) ^ (ln & 7)) << 3)];
      const int br = wc * 64 + i * 16 + ln;
      b0[i] = *(const bfrag*)&Bs[br * 64 + (((g + 0) ^ (ln & 7)) << 3)];
      b1[i] = *(const bfrag*)&Bs[br * 64 + (((g + 4) ^ (ln & 7)) << 3)];
    }
    if (isV) {
      #pragma unroll
      for (int i = 0; i < 4; i++)
        #pragma unroll
        for (int j = 0; j < 4; j++) {
          acc[i][j] = __builtin_amdgcn_mfma_f32_16x16x32_bf16(b0[i], a0[j], acc[i][j], 0, 0, 0);
          acc[i][j] = __builtin_amdgcn_mfma_f32_16x16x32_bf16(b1[i], a1[j], acc[i][j], 0, 0, 0);
        }
    } else {
      #pragma unroll
      for (int i = 0; i < 4; i++)
        #pragma unroll
        for (int j = 0; j < 4; j++) {
          acc[i][j] = __builtin_amdgcn_mfma_f32_16x16x32_bf16(a0[i], b0[j], acc[i][j], 0, 0, 0);
          acc[i][j] = __builtin_amdgcn_mfma_f32_16x16x32_bf16(a1[i], b1[j], acc[i][j], 0, 0, 0);
        }
    }
  }

  // C/D layout (m89): col = lane&15, row = (lane>>4)*4 + reg
  if (MODE == 0 && !isV) {
    #pragma unroll
    for (int j = 0; j < 4; j++) {
      const int n = n0 + wc * 64 + j * 16 + ln;       // < 768
      const float bn = bias[n];
      const int h = n >> 6, d = n & 63;
      #pragma unroll
      for (int i = 0; i < 4; i++)
        #pragma unroll
        for (int r = 0; r < 4; r++) {
          const int m = m0 + wr * 64 + i * 16 + g * 4 + r;
          kb[(((size_t)((m >> 12) * kH + h)) * kL + (m & 4095)) * kD + d] =
              f2bf(acc[i][j][r] + bn);
        }
    }
  } else if (MODE == 0) {
    #pragma unroll
    for (int i = 0; i < 4; i++)
      #pragma unroll
      for (int r = 0; r < 4; r++) {
        const int n = n0 + wc * 64 + i * 16 + g * 4 + r;   // >= 768
        const float bn = bias[n];
        const int nn = n - kHID;
        const int h = nn >> 6, d = nn & 63;
        #pragma unroll
        for (int j = 0; j < 4; j++) {
          const int m = m0 + wr * 64 + j * 16 + ln;
          vt[(((size_t)((m >> 12) * kH + h)) * kD + d) * kL + (m & 4095)] =
              f2bf(acc[i][j][r] + bn);
        }
      }
  } else {
    #pragma unroll
    for (int j = 0; j < 4; j++) {
      const int n = n0 + wc * 64 + j * 16 + ln;
      const float bn = bias[n];
      #pragma unroll
      for (int i = 0; i < 4; i++)
        #pragma unroll
        for (int r = 0; r < 4; r++) {
          const int m = m0 + wr * 64 + i * 16 + g * 4 + r;
          const size_t off = (size_t)m * kHID + n;
          outf[off] = acc[i][j][r] + bn + resid[off];
        }
    }
  }
}

// ---------------------------------------------------------------------------
// Kernel 3: flash attention, MFMA 16x16x32 bf16.
// grid (S/64, H, B), 256 thr = 4 waves (16 q-rows each).
// HYBRID of R5 (proven coalesced LDS staging of K and V^T tiles, XOR-chunk
// swizzle, 2 barriers/tile, 0 conflicts) and R6's cheap softmax:
// swapped QK^T (lane owns q=lane&15), 2-shuffle row reduce (xor 16,32),
// exp2 domain (scale pre-folded into Q), zero-threshold defer-max, bitmask.
// Next tile's staging loads are issued right after the 2nd barrier so
// HBM/L2 latency hides under this tile's compute (T14-lite).
// ---------------------------------------------------------------------------
__global__ __launch_bounds__(256, 3) void attn_mfma(
    const short* __restrict__ qbf, const short* __restrict__ kbuf,
    const short* __restrict__ vtbuf, const unsigned long long* __restrict__ pmask,
    short* __restrict__ attn_out)
{
  __shared__ short Ks[64 * 64];   // [l][d], 16B-chunk XOR-swizzled by (row&7)
  __shared__ short Vs[64 * 64];   // [d][l], same swizzle
  __shared__ short Ps[4][16 * 64];

  const int qt = blockIdx.x, h = blockIdx.y, b = blockIdx.z;
  const int s0 = qt * 64;
  const int t = threadIdx.x;
  const int wv = t >> 6, lane = t & 63;
  const int g = lane >> 4, ln = lane & 15;

  const short* Kg = kbuf + ((size_t)(b * kH + h)) * kL * kD;
  const short* Vg = vtbuf + ((size_t)(b * kH + h)) * kD * kL;

  // Q (B-operand): lane holds col q = ln, k-chunks g / g+4. Pre-scaled.
  const short* qrow = qbf + ((size_t)(b * kS + s0 + wv * 16 + ln)) * kHID + h * kD;
  const bfrag bQ0 = *(const bfrag*)(qrow + g * 8);
  const bfrag bQ1 = *(const bfrag*)(qrow + 32 + g * 8);

  const unsigned long long* pmrow =
      pmask + ((size_t)(b * kS + s0 + wv * 16 + ln)) * 32;

  short* myPs = &Ps[wv][0];
  const int rdP0 = ln * 64 + (((g + 0) ^ (ln & 7)) << 3);
  const int rdP1 = ln * 64 + (((g + 4) ^ (ln & 7)) << 3);

  // staging coords: thread t covers row srow, 32-byte pair sc4 (R5 pattern)
  const int srow = t >> 2, sc4 = t & 3;
  const int swz0 = srow * 64 + (((sc4 * 2 + 0) ^ (srow & 7)) << 3);
  const int swz1 = srow * 64 + (((sc4 * 2 + 1) ^ (srow & 7)) << 3);
  const short* kgp0 = Kg + (size_t)srow * kD + sc4 * 16;
  const short* vgp0 = Vg + (size_t)srow * kL + sc4 * 16;

  f32x4 accO[4] = {};
  float mrun = -FLT_MAX, lrun = 0.f;
  const f32x4 zero = {0.f, 0.f, 0.f, 0.f};

  // prologue: load tile 0 into staging regs
  uint4 ka  = *(const uint4*)(kgp0);
  uint4 kb2 = *(const uint4*)(kgp0 + 8);
  uint4 va  = *(const uint4*)(vgp0);
  uint4 vb  = *(const uint4*)(vgp0 + 8);

  for (int lt = 0; lt < kL / 64; lt++) {
    __syncthreads();   // all waves done reading previous Ks/Vs
    *(uint4*)&Ks[swz0] = ka;
    *(uint4*)&Ks[swz1] = kb2;
    *(uint4*)&Vs[swz0] = va;
    *(uint4*)&Vs[swz1] = vb;
    __syncthreads();
    if (lt + 1 < kL / 64) {     // prefetch next tile (overlaps compute below)
      const short* kn = kgp0 + (size_t)(lt + 1) * 64 * kD;
      ka  = *(const uint4*)(kn);
      kb2 = *(const uint4*)(kn + 8);
      const short* vn = vgp0 + (lt + 1) * 64;
      va  = *(const uint4*)(vn);
      vb  = *(const uint4*)(vn + 8);
    }

    // ---- fragments from LDS (2-way aliased reads = free) ----
    bfrag aK0[4], aK1[4], bV0[4], bV1[4];
    #pragma unroll
    for (int nt = 0; nt < 4; nt++) {
      const int row = nt * 16 + ln;
      aK0[nt] = *(const bfrag*)&Ks[row * 64 + (((g + 0) ^ (ln & 7)) << 3)];
      aK1[nt] = *(const bfrag*)&Ks[row * 64 + (((g + 4) ^ (ln & 7)) << 3)];
      bV0[nt] = *(const bfrag*)&Vs[row * 64 + (((g + 0) ^ (ln & 7)) << 3)];
      bV1[nt] = *(const bfrag*)&Vs[row * 64 + (((g + 4) ^ (ln & 7)) << 3)];
    }

    // ---- S^T = K·Q^T : D[l][q], lane col q=ln, row l = nt*16 + g*4 + r ----
    f32x4 accS[4];
    #pragma unroll
    for (int nt = 0; nt < 4; nt++) {
      accS[nt] = __builtin_amdgcn_mfma_f32_16x16x32_bf16(aK0[nt], bQ0, zero, 0, 0, 0);
      accS[nt] = __builtin_amdgcn_mfma_f32_16x16x32_bf16(aK1[nt], bQ1, accS[nt], 0, 0, 0);
    }

    // ---- mask (decoder half): bit index l = nt*16 + g*4 + r ----
    if (lt >= kSE / 64) {
      const unsigned long long wm = pmrow[lt - kSE / 64];
      #pragma unroll
      for (int nt = 0; nt < 4; nt++) {
        const unsigned nib = (unsigned)(wm >> (nt * 16 + g * 4)) & 0xFu;
        #pragma unroll
        for (int r = 0; r < 4; r++)
          if (!((nib >> r) & 1u)) accS[nt][r] = -FLT_MAX;
      }
    }

    // ---- row max: 16 local + 2 shuffles (lanes xor 16, 32 share q-row) ----
    float pmax = accS[0][0];
    #pragma unroll
    for (int nt = 0; nt < 4; nt++)
      #pragma unroll
      for (int r = 0; r < 4; r++) pmax = fmaxf(pmax, accS[nt][r]);
    pmax = fmaxf(pmax, __shfl_xor(pmax, 16, 64));
    pmax = fmaxf(pmax, __shfl_xor(pmax, 32, 64));

    // ---- defer-max (threshold 0: mathematically exact) ----
    if (!__all(pmax <= mrun)) {
      const float mn = fmaxf(mrun, pmax);
      const float corr = exp2f(mrun - mn);
      mrun = mn;
      lrun *= corr;
      float c4[4];
      #pragma unroll
      for (int r = 0; r < 4; r++) c4[r] = __shfl(corr, g * 4 + r, 64);
      #pragma unroll
      for (int nt = 0; nt < 4; nt++) {
        accO[nt][0] *= c4[0]; accO[nt][1] *= c4[1];
        accO[nt][2] *= c4[2]; accO[nt][3] *= c4[3];
      }
    }

    // ---- P = 2^(S - m), row sum ----
    float ps = 0.f;
    #pragma unroll
    for (int nt = 0; nt < 4; nt++)
      #pragma unroll
      for (int r = 0; r < 4; r++) {
        const float p = exp2f(accS[nt][r] - mrun);
        accS[nt][r] = p;
        ps += p;
      }
    ps += __shfl_xor(ps, 16, 64);
    ps += __shfl_xor(ps, 32, 64);
    lrun += ps;

    // ---- pack P (bf16) into per-wave LDS, chunk-swizzled ----
    #pragma unroll
    for (int nt = 0; nt < 4; nt++) {
      short4 p4 = {f2bf(accS[nt][0]), f2bf(accS[nt][1]),
                   f2bf(accS[nt][2]), f2bf(accS[nt][3])};
      const int chunk = nt * 2 + (g >> 1);            // (nt*16+g*4) >> 3
      const int sc = chunk ^ (ln & 7);
      *(short4*)&myPs[ln * 64 + sc * 8 + (g & 1) * 4] = p4;
    }

    // ---- PV: O[q][d] += P·V (A = P row q=ln, B = V^T col d from LDS) ----
    const bfrag aP0 = *(const bfrag*)&myPs[rdP0];
    const bfrag aP1 = *(const bfrag*)&myPs[rdP1];
    #pragma unroll
    for (int nt = 0; nt < 4; nt++) {
      accO[nt] = __builtin_amdgcn_mfma_f32_16x16x32_bf16(aP0, bV0[nt], accO[nt], 0, 0, 0);
      accO[nt] = __builtin_amdgcn_mfma_f32_16x16x32_bf16(aP1, bV1[nt], accO[nt], 0, 0, 0);
    }
  }

  // ---- normalize + store: row q = g*4+r, col d = nt*16+ln ----
  const float linv = 1.0f / lrun;
  float i4[4];
  #pragma unroll
  for (int r = 0; r < 4; r++) i4[r] = __shfl(linv, g * 4 + r, 64);
  #pragma unroll
  for (int nt = 0; nt < 4; nt++)
    #pragma unroll
    for (int r = 0; r < 4; r++) {
      const int q = s0 + wv * 16 + g * 4 + r;
      attn_out[((size_t)(b * kS + q)) * kHID + h * kD + nt * 16 + ln] =
          f2bf(accO[nt][r] * i4[r]);
    }
}

// ---------------------------------------------------------------------------
extern "C" void kernel_launch(void* const* d_in, const int* in_sizes, int n_in,
                              void* d_out, int out_size, void* d_ws, size_t ws_size,
                              hipStream_t stream) {
  const float* q_in    = (const float*)d_in[0];
  const float* kv_in   = (const float*)d_in[1];
  const float* enc     = (const float*)d_in[2];
  const unsigned char* am = (const unsigned char*)d_in[3];
  const unsigned char* dm = (const unsigned char*)d_in[4];
  // d_in[5], d_in[6]: Wq (computed-then-discarded in reference) -> skipped
  const float* wkv_w   = (const float*)d_in[7];
  const float* wkv_b   = (const float*)d_in[8];
  const float* dense_w = (const float*)d_in[9];
  const float* dense_b = (const float*)d_in[10];
  const float* norm_g  = (const float*)d_in[11];
  const float* norm_b  = (const float*)d_in[12];
  float* out = (float*)d_out;

  float* ws = (float*)d_ws;
  float* q_hs   = ws;                                 // f32 [B,S,HID]   3,145,728 f
  short* ekv    = (short*)(ws + 3145728);             // bf16 [B,L,HID]  (3,145,728 f)
  short* kbuf   = (short*)(ws + 6291456);             // bf16 [B,H,L,D]  (3,145,728 f)
  short* vtbuf  = (short*)(ws + 9437184);             // bf16 [B,H,D,L]  (3,145,728 f)
  short* qbf    = (short*)(ws + 12582912);            // bf16 [B,S,HID]  (1,572,864 f)
  unsigned long long* pmask = (unsigned long long*)(ws + 14155776); // [B,S,32] u64
  short* wkv_bf = (short*)(ws + 14417920);            // bf16 [1536,768] (589,824 f)
  short* wd_bf  = (short*)(ws + 15007744);            // bf16 [768,768]  (294,912 f)
  short* attn_bf = ekv;                               // alias: ekv dead after KV GEMM

  hipLaunchKernelGGL(ln_copy_kernel, dim3(kB * kS, 3), dim3(256), 0, stream,
                     q_in, kv_in, enc, norm_g, norm_b, q_hs, ekv, qbf);
  hipLaunchKernelGGL(mask_pack_kernel, dim3(kB * kS), dim3(64), 0, stream,
                     am, dm, pmask);
  hipLaunchKernelGGL(cvt_w_kernel, dim3(1024), dim3(256), 0, stream,
                     wkv_w, dense_w, wkv_bf, wd_bf);
  hipLaunchKernelGGL((gemm_mfma<0>), dim3(64, 12), dim3(256), 0, stream,
                     ekv, wkv_bf, wkv_b, kbuf, vtbuf, nullptr, nullptr);
  hipLaunchKernelGGL(attn_mfma, dim3(kS / 64, kH, kB), dim3(256), 0, stream,
                     qbf, kbuf, vtbuf, pmask, attn_bf);
  hipLaunchKernelGGL((gemm_mfma<1>), dim3(32, 6), dim3(256), 0, stream,
                     attn_bf, wd_bf, dense_b, nullptr, nullptr, out, q_hs);
}

// Round 12
// 416.200 us; speedup vs baseline: 1.5722x; 1.0326x over previous
//
#include <hip/hip_runtime.h>
#include <hip/hip_bf16.h>
#include <float.h>

// Problem constants
constexpr int kB = 2, kS = 2048, kSE = 2048, kL = 4096, kHID = 768, kH = 12, kD = 64;

typedef __attribute__((ext_vector_type(8))) short bfrag;   // 8 bf16 (4 VGPRs)
typedef __attribute__((ext_vector_type(4))) float f32x4;   // 4 fp32 acc

// RNE float->bf16 via compiler-lowered cvt (m240: don't hand-write cvt_pk)
__device__ __forceinline__ short f2bf(float x) {
  __hip_bfloat16 h = __float2bfloat16(x);
  short s;
  __builtin_memcpy(&s, &h, 2);
  return s;
}

// softmax uses exp2; fold 1/sqrt(64) * log2(e) into Q at LN time
#define QSCALE (0.125f * 1.44269504088896340736f)

// ---------------------------------------------------------------------------
// Kernel 1: LayerNorm (q and kv) + copy encoder_output into bf16 ekv buffer.
// ---------------------------------------------------------------------------
__global__ __launch_bounds__(256) void ln_copy_kernel(
    const float* __restrict__ qin, const float* __restrict__ kvin,
    const float* __restrict__ enc, const float* __restrict__ g,
    const float* __restrict__ beta, float* __restrict__ q_hs,
    short* __restrict__ ekv, short* __restrict__ qbf)
{
  const int row = blockIdx.x;            // b*2048 + s
  const int mode = blockIdx.y;
  const int t = threadIdx.x;
  const int b = row >> 11, s = row & 2047;

  if (mode == 2) {
    const float4* src = (const float4*)(enc + (size_t)row * kHID);
    short* dst = ekv + ((size_t)b * kL + s) * kHID;
    if (t < 192) {
      float4 v = src[t];
      short4 o = {f2bf(v.x), f2bf(v.y), f2bf(v.z), f2bf(v.w)};
      *(short4*)(dst + t * 4) = o;
    }
    return;
  }

  const float* x = (mode == 0 ? qin : kvin) + (size_t)row * kHID;
  float v0 = x[t], v1 = x[t + 256], v2 = x[t + 512];
  float sum = v0 + v1 + v2;
  float sq  = v0 * v0 + v1 * v1 + v2 * v2;
  #pragma unroll
  for (int off = 32; off > 0; off >>= 1) {
    sum += __shfl_down(sum, off, 64);
    sq  += __shfl_down(sq,  off, 64);
  }
  __shared__ float red[8];
  const int wave = t >> 6;
  if ((t & 63) == 0) { red[wave] = sum; red[wave + 4] = sq; }
  __syncthreads();
  const float tsum = red[0] + red[1] + red[2] + red[3];
  const float tsq  = red[4] + red[5] + red[6] + red[7];
  const float mu   = tsum * (1.0f / kHID);
  const float var  = tsq * (1.0f / kHID) - mu * mu;
  const float rstd = rsqrtf(var + 1e-12f);

  const float o0 = (v0 - mu) * rstd * g[t]       + beta[t];
  const float o1 = (v1 - mu) * rstd * g[t + 256] + beta[t + 256];
  const float o2 = (v2 - mu) * rstd * g[t + 512] + beta[t + 512];

  if (mode == 0) {
    float* out = q_hs + (size_t)row * kHID;
    out[t] = o0; out[t + 256] = o1; out[t + 512] = o2;
    short* ob = qbf + (size_t)row * kHID;
    ob[t]       = f2bf(o0 * QSCALE);
    ob[t + 256] = f2bf(o1 * QSCALE);
    ob[t + 512] = f2bf(o2 * QSCALE);
  } else {
    short* out = ekv + ((size_t)b * kL + kSE + s) * kHID;
    out[t] = f2bf(o0); out[t + 256] = f2bf(o1); out[t + 512] = f2bf(o2);
  }
}

// ---------------------------------------------------------------------------
// Kernel 1b: pack (am & dm & ~eye) into bit-mask words [B][S][32] u64.
// ---------------------------------------------------------------------------
__global__ __launch_bounds__(64) void mask_pack_kernel(
    const unsigned char* __restrict__ am, const unsigned char* __restrict__ dm,
    unsigned long long* __restrict__ pmask)
{
  const int row = blockIdx.x;            // b*2048 + s
  const int b = row >> 11, s = row & 2047;
  const int lane = threadIdx.x;
  const unsigned char* dmr = dm + (size_t)row * kS;
  const unsigned char* amr = am + (size_t)b * kS;
  #pragma unroll 4
  for (int w = 0; w < 32; w++) {
    const int le = w * 64 + lane;
    const bool v = amr[le] && dmr[le] && (s != le);
    const unsigned long long word = __ballot(v);
    if (lane == 0) pmask[(size_t)row * 32 + w] = word;
  }
}

// ---------------------------------------------------------------------------
// Kernel 1c: convert Wkv and dense_w to bf16 (one shot).
// ---------------------------------------------------------------------------
__global__ __launch_bounds__(256) void cvt_w_kernel(
    const float* __restrict__ w1, const float* __restrict__ w2,
    short* __restrict__ o1, short* __restrict__ o2)
{
  const int n1 = 2 * kHID * kHID;
  const int n2 = kHID * kHID;
  const int tot = (n1 + n2) / 4;
  for (int idx = blockIdx.x * 256 + threadIdx.x; idx < tot; idx += gridDim.x * 256) {
    const int i4 = idx * 4;
    if (i4 < n1) {
      float4 v = *(const float4*)(w1 + i4);
      short4 o = {f2bf(v.x), f2bf(v.y), f2bf(v.z), f2bf(v.w)};
      *(short4*)(o1 + i4) = o;
    } else {
      float4 v = *(const float4*)(w2 + (i4 - n1));
      short4 o = {f2bf(v.x), f2bf(v.y), f2bf(v.z), f2bf(v.w)};
      *(short4*)(o2 + (i4 - n1)) = o;
    }
  }
}

// ---------------------------------------------------------------------------
// Kernel 2: bf16 MFMA GEMM. 128x128 tile, BK=64, 4 waves (2x2), 4x4 frags.
// MODE 0: merged KV projection, grid (64,12); n0<768 -> K [B,H,L,D];
//         n0>=768 -> V (swapped operands) -> V^T [B,H,D,L].
//   Epilogue goes through a 32 KB LDS tile (aliased over As/Bs) so the
//   global stores are dense 128-256B runs instead of 2B/32B scatters (the
//   R9 counters showed 216us @ ~0% util from store-pipe serialization).
// MODE 1: dense + bias + resid -> fp32 out, grid (32,6)  (epilogue direct).
// ---------------------------------------------------------------------------
union GemmSmem {
  struct { short A[128 * 64]; short B[128 * 64]; } ab;
  short E[128 * 128];
};

template <int MODE>
__global__ __launch_bounds__(256) void gemm_mfma(
    const short* __restrict__ A, const short* __restrict__ W,
    const float* __restrict__ bias, short* __restrict__ kb,
    short* __restrict__ vt, float* __restrict__ outf,
    const float* __restrict__ resid)
{
  __shared__ GemmSmem sm;
  short* As = sm.ab.A;
  short* Bs = sm.ab.B;
  const int t = threadIdx.x;
  const int m0 = blockIdx.x * 128;
  const int n0 = blockIdx.y * 128;
  const bool isV = (MODE == 0) && (n0 >= kHID);
  const int wv = t >> 6, lane = t & 63;
  const int g = lane >> 4, ln = lane & 15;
  const int wr = wv >> 1, wc = wv & 1;

  f32x4 acc[4][4] = {};   // K/dense: [i=m][j=n]; V: [i=n][j=m]

  for (int kt = 0; kt < kHID; kt += 64) {
    uint4 ra[4], rb[4];
    #pragma unroll
    for (int r = 0; r < 4; r++) {
      const int f = t + r * 256;
      const int row = f >> 3, c = f & 7;
      ra[r] = *(const uint4*)(A + (size_t)(m0 + row) * kHID + kt + c * 8);
      rb[r] = *(const uint4*)(W + (size_t)(n0 + row) * kHID + kt + c * 8);
    }
    __syncthreads();
    #pragma unroll
    for (int r = 0; r < 4; r++) {
      const int f = t + r * 256;
      const int row = f >> 3, c = f & 7;
      const int sc = c ^ (row & 7);
      *(uint4*)&As[row * 64 + sc * 8] = ra[r];
      *(uint4*)&Bs[row * 64 + sc * 8] = rb[r];
    }
    __syncthreads();

    bfrag a0[4], a1[4], b0[4], b1[4];
    #pragma unroll
    for (int i = 0; i < 4; i++) {
      const int ar = wr * 64 + i * 16 + ln;
      a0[i] = *(const bfrag*)&As[ar * 64 + (((g + 0) ^ (ln & 7)) << 3)];
      a1[i] = *(const bfrag*)&As[ar * 64 + (((g + 4) ^ (ln & 7)) << 3)];
      const int br = wc * 64 + i * 16 + ln;
      b0[i] = *(const bfrag*)&Bs[br * 64 + (((g + 0) ^ (ln & 7)) << 3)];
      b1[i] = *(const bfrag*)&Bs[br * 64 + (((g + 4) ^ (ln & 7)) << 3)];
    }
    if (isV) {
      #pragma unroll
      for (int i = 0; i < 4; i++)
        #pragma unroll
        for (int j = 0; j < 4; j++) {
          acc[i][j] = __builtin_amdgcn_mfma_f32_16x16x32_bf16(b0[i], a0[j], acc[i][j], 0, 0, 0);
          acc[i][j] = __builtin_amdgcn_mfma_f32_16x16x32_bf16(b1[i], a1[j], acc[i][j], 0, 0, 0);
        }
    } else {
      #pragma unroll
      for (int i = 0; i < 4; i++)
        #pragma unroll
        for (int j = 0; j < 4; j++) {
          acc[i][j] = __builtin_amdgcn_mfma_f32_16x16x32_bf16(a0[i], b0[j], acc[i][j], 0, 0, 0);
          acc[i][j] = __builtin_amdgcn_mfma_f32_16x16x32_bf16(a1[i], b1[j], acc[i][j], 0, 0, 0);
        }
    }
  }

  // C/D layout (m89): col = lane&15, row = (lane>>4)*4 + reg
  if (MODE == 0) {
    // ---- LDS-transpose epilogue ----
    __syncthreads();            // all fragment reads of As/Bs done
    short* Es = sm.E;
    const int bb = m0 >> 12;    // 128-row blocks never straddle b
    const int hb = (isV ? (n0 - kHID) : n0) >> 6;   // first of 2 heads

    if (!isV) {
      // K: Es[m][n] (m = l-row, n = (h,d) contiguous axis)
      #pragma unroll
      for (int j = 0; j < 4; j++) {
        const int nl = wc * 64 + j * 16 + ln;
        const float bn = bias[n0 + nl];
        #pragma unroll
        for (int i = 0; i < 4; i++)
          #pragma unroll
          for (int r = 0; r < 4; r++) {
            const int ml = wr * 64 + i * 16 + g * 4 + r;
            Es[ml * 128 + (((nl >> 3) ^ (ml & 15)) << 3) + (nl & 7)] =
                f2bf(acc[i][j][r] + bn);
          }
      }
      __syncthreads();
      // copy out: row = m (l), 16 chunks of 8 shorts cover (h,d)
      #pragma unroll
      for (int p = 0; p < 8; p++) {
        const int idx = p * 256 + t;
        const int row = idx >> 4, c8 = idx & 15;
        uint4 v = *(const uint4*)&Es[row * 128 + ((c8 ^ (row & 15)) << 3)];
        const int h = hb + (c8 >> 3), d0 = (c8 & 7) * 8;
        const int l = (m0 & 4095) + row;
        *(uint4*)(kb + (((size_t)(bb * kH + h)) * kL + l) * kD + d0) = v;
      }
    } else {
      // V: Es[n][m] (n = (h,d) row, m = l contiguous axis)
      #pragma unroll
      for (int i = 0; i < 4; i++)
        #pragma unroll
        for (int r = 0; r < 4; r++) {
          const int nl = wc * 64 + i * 16 + g * 4 + r;
          const float bn = bias[n0 + nl];
          #pragma unroll
          for (int j = 0; j < 4; j++) {
            const int ml = wr * 64 + j * 16 + ln;
            Es[nl * 128 + (((ml >> 3) ^ (nl & 15)) << 3) + (ml & 7)] =
                f2bf(acc[i][j][r] + bn);
          }
        }
      __syncthreads();
      // copy out: row = n -> (h,d); 16 chunks of 8 shorts cover l
      #pragma unroll
      for (int p = 0; p < 8; p++) {
        const int idx = p * 256 + t;
        const int row = idx >> 4, c8 = idx & 15;
        uint4 v = *(const uint4*)&Es[row * 128 + ((c8 ^ (row & 15)) << 3)];
        const int h = hb + (row >> 6), d = row & 63;
        const int l0 = (m0 & 4095) + c8 * 8;
        *(uint4*)(vt + (((size_t)(bb * kH + h)) * kD + d) * kL + l0) = v;
      }
    }
  } else {
    #pragma unroll
    for (int j = 0; j < 4; j++) {
      const int n = n0 + wc * 64 + j * 16 + ln;
      const float bn = bias[n];
      #pragma unroll
      for (int i = 0; i < 4; i++)
        #pragma unroll
        for (int r = 0; r < 4; r++) {
          const int m = m0 + wr * 64 + i * 16 + g * 4 + r;
          const size_t off = (size_t)m * kHID + n;
          outf[off] = acc[i][j][r] + bn + resid[off];
        }
    }
  }
}

// ---------------------------------------------------------------------------
// Kernel 3: flash attention, MFMA 16x16x32 bf16 (unchanged from R9: hybrid
// LDS staging + cheap swapped-QK^T softmax; 141us, matched prediction).
// ---------------------------------------------------------------------------
__global__ __launch_bounds__(256, 3) void attn_mfma(
    const short* __restrict__ qbf, const short* __restrict__ kbuf,
    const short* __restrict__ vtbuf, const unsigned long long* __restrict__ pmask,
    short* __restrict__ attn_out)
{
  __shared__ short Ks[64 * 64];   // [l][d], 16B-chunk XOR-swizzled by (row&7)
  __shared__ short Vs[64 * 64];   // [d][l], same swizzle
  __shared__ short Ps[4][16 * 64];

  const int qt = blockIdx.x, h = blockIdx.y, b = blockIdx.z;
  const int s0 = qt * 64;
  const int t = threadIdx.x;
  const int wv = t >> 6, lane = t & 63;
  const int g = lane >> 4, ln = lane & 15;

  const short* Kg = kbuf + ((size_t)(b * kH + h)) * kL * kD;
  const short* Vg = vtbuf + ((size_t)(b * kH + h)) * kD * kL;

  const short* qrow = qbf + ((size_t)(b * kS + s0 + wv * 16 + ln)) * kHID + h * kD;
  const bfrag bQ0 = *(const bfrag*)(qrow + g * 8);
  const bfrag bQ1 = *(const bfrag*)(qrow + 32 + g * 8);

  const unsigned long long* pmrow =
      pmask + ((size_t)(b * kS + s0 + wv * 16 + ln)) * 32;

  short* myPs = &Ps[wv][0];
  const int rdP0 = ln * 64 + (((g + 0) ^ (ln & 7)) << 3);
  const int rdP1 = ln * 64 + (((g + 4) ^ (ln & 7)) << 3);

  const int srow = t >> 2, sc4 = t & 3;
  const int swz0 = srow * 64 + (((sc4 * 2 + 0) ^ (srow & 7)) << 3);
  const int swz1 = srow * 64 + (((sc4 * 2 + 1) ^ (srow & 7)) << 3);
  const short* kgp0 = Kg + (size_t)srow * kD + sc4 * 16;
  const short* vgp0 = Vg + (size_t)srow * kL + sc4 * 16;

  f32x4 accO[4] = {};
  float mrun = -FLT_MAX, lrun = 0.f;
  const f32x4 zero = {0.f, 0.f, 0.f, 0.f};

  uint4 ka  = *(const uint4*)(kgp0);
  uint4 kb2 = *(const uint4*)(kgp0 + 8);
  uint4 va  = *(const uint4*)(vgp0);
  uint4 vb  = *(const uint4*)(vgp0 + 8);

  for (int lt = 0; lt < kL / 64; lt++) {
    __syncthreads();
    *(uint4*)&Ks[swz0] = ka;
    *(uint4*)&Ks[swz1] = kb2;
    *(uint4*)&Vs[swz0] = va;
    *(uint4*)&Vs[swz1] = vb;
    __syncthreads();
    if (lt + 1 < kL / 64) {
      const short* kn = kgp0 + (size_t)(lt + 1) * 64 * kD;
      ka  = *(const uint4*)(kn);
      kb2 = *(const uint4*)(kn + 8);
      const short* vn = vgp0 + (lt + 1) * 64;
      va  = *(const uint4*)(vn);
      vb  = *(const uint4*)(vn + 8);
    }

    bfrag aK0[4], aK1[4], bV0[4], bV1[4];
    #pragma unroll
    for (int nt = 0; nt < 4; nt++) {
      const int row = nt * 16 + ln;
      aK0[nt] = *(const bfrag*)&Ks[row * 64 + (((g + 0) ^ (ln & 7)) << 3)];
      aK1[nt] = *(const bfrag*)&Ks[row * 64 + (((g + 4) ^ (ln & 7)) << 3)];
      bV0[nt] = *(const bfrag*)&Vs[row * 64 + (((g + 0) ^ (ln & 7)) << 3)];
      bV1[nt] = *(const bfrag*)&Vs[row * 64 + (((g + 4) ^ (ln & 7)) << 3)];
    }

    f32x4 accS[4];
    #pragma unroll
    for (int nt = 0; nt < 4; nt++) {
      accS[nt] = __builtin_amdgcn_mfma_f32_16x16x32_bf16(aK0[nt], bQ0, zero, 0, 0, 0);
      accS[nt] = __builtin_amdgcn_mfma_f32_16x16x32_bf16(aK1[nt], bQ1, accS[nt], 0, 0, 0);
    }

    if (lt >= kSE / 64) {
      const unsigned long long wm = pmrow[lt - kSE / 64];
      #pragma unroll
      for (int nt = 0; nt < 4; nt++) {
        const unsigned nib = (unsigned)(wm >> (nt * 16 + g * 4)) & 0xFu;
        #pragma unroll
        for (int r = 0; r < 4; r++)
          if (!((nib >> r) & 1u)) accS[nt][r] = -FLT_MAX;
      }
    }

    float pmax = accS[0][0];
    #pragma unroll
    for (int nt = 0; nt < 4; nt++)
      #pragma unroll
      for (int r = 0; r < 4; r++) pmax = fmaxf(pmax, accS[nt][r]);
    pmax = fmaxf(pmax, __shfl_xor(pmax, 16, 64));
    pmax = fmaxf(pmax, __shfl_xor(pmax, 32, 64));

    if (!__all(pmax <= mrun)) {
      const float mn = fmaxf(mrun, pmax);
      const float corr = exp2f(mrun - mn);
      mrun = mn;
      lrun *= corr;
      float c4[4];
      #pragma unroll
      for (int r = 0; r < 4; r++) c4[r] = __shfl(corr, g * 4 + r, 64);
      #pragma unroll
      for (int nt = 0; nt < 4; nt++) {
        accO[nt][0] *= c4[0]; accO[nt][1] *= c4[1];
        accO[nt][2] *= c4[2]; accO[nt][3] *= c4[3];
      }
    }

    float ps = 0.f;
    #pragma unroll
    for (int nt = 0; nt < 4; nt++)
      #pragma unroll
      for (int r = 0; r < 4; r++) {
        const float p = exp2f(accS[nt][r] - mrun);
        accS[nt][r] = p;
        ps += p;
      }
    ps += __shfl_xor(ps, 16, 64);
    ps += __shfl_xor(ps, 32, 64);
    lrun += ps;

    #pragma unroll
    for (int nt = 0; nt < 4; nt++) {
      short4 p4 = {f2bf(accS[nt][0]), f2bf(accS[nt][1]),
                   f2bf(accS[nt][2]), f2bf(accS[nt][3])};
      const int chunk = nt * 2 + (g >> 1);            // (nt*16+g*4) >> 3
      const int sc = chunk ^ (ln & 7);
      *(short4*)&myPs[ln * 64 + sc * 8 + (g & 1) * 4] = p4;
    }

    const bfrag aP0 = *(const bfrag*)&myPs[rdP0];
    const bfrag aP1 = *(const bfrag*)&myPs[rdP1];
    #pragma unroll
    for (int nt = 0; nt < 4; nt++) {
      accO[nt] = __builtin_amdgcn_mfma_f32_16x16x32_bf16(aP0, bV0[nt], accO[nt], 0, 0, 0);
      accO[nt] = __builtin_amdgcn_mfma_f32_16x16x32_bf16(aP1, bV1[nt], accO[nt], 0, 0, 0);
    }
  }

  const float linv = 1.0f / lrun;
  float i4[4];
  #pragma unroll
  for (int r = 0; r < 4; r++) i4[r] = __shfl(linv, g * 4 + r, 64);
  #pragma unroll
  for (int nt = 0; nt < 4; nt++)
    #pragma unroll
    for (int r = 0; r < 4; r++) {
      const int q = s0 + wv * 16 + g * 4 + r;
      attn_out[((size_t)(b * kS + q)) * kHID + h * kD + nt * 16 + ln] =
          f2bf(accO[nt][r] * i4[r]);
    }
}

// ---------------------------------------------------------------------------
extern "C" void kernel_launch(void* const* d_in, const int* in_sizes, int n_in,
                              void* d_out, int out_size, void* d_ws, size_t ws_size,
                              hipStream_t stream) {
  const float* q_in    = (const float*)d_in[0];
  const float* kv_in   = (const float*)d_in[1];
  const float* enc     = (const float*)d_in[2];
  const unsigned char* am = (const unsigned char*)d_in[3];
  const unsigned char* dm = (const unsigned char*)d_in[4];
  // d_in[5], d_in[6]: Wq (computed-then-discarded in reference) -> skipped
  const float* wkv_w   = (const float*)d_in[7];
  const float* wkv_b   = (const float*)d_in[8];
  const float* dense_w = (const float*)d_in[9];
  const float* dense_b = (const float*)d_in[10];
  const float* norm_g  = (const float*)d_in[11];
  const float* norm_b  = (const float*)d_in[12];
  float* out = (float*)d_out;

  float* ws = (float*)d_ws;
  float* q_hs   = ws;                                 // f32 [B,S,HID]   3,145,728 f
  short* ekv    = (short*)(ws + 3145728);             // bf16 [B,L,HID]  (3,145,728 f)
  short* kbuf   = (short*)(ws + 6291456);             // bf16 [B,H,L,D]  (3,145,728 f)
  short* vtbuf  = (short*)(ws + 9437184);             // bf16 [B,H,D,L]  (3,145,728 f)
  short* qbf    = (short*)(ws + 12582912);            // bf16 [B,S,HID]  (1,572,864 f)
  unsigned long long* pmask = (unsigned long long*)(ws + 14155776); // [B,S,32] u64
  short* wkv_bf = (short*)(ws + 14417920);            // bf16 [1536,768] (589,824 f)
  short* wd_bf  = (short*)(ws + 15007744);            // bf16 [768,768]  (294,912 f)
  short* attn_bf = ekv;                               // alias: ekv dead after KV GEMM

  hipLaunchKernelGGL(ln_copy_kernel, dim3(kB * kS, 3), dim3(256), 0, stream,
                     q_in, kv_in, enc, norm_g, norm_b, q_hs, ekv, qbf);
  hipLaunchKernelGGL(mask_pack_kernel, dim3(kB * kS), dim3(64), 0, stream,
                     am, dm, pmask);
  hipLaunchKernelGGL(cvt_w_kernel, dim3(1024), dim3(256), 0, stream,
                     wkv_w, dense_w, wkv_bf, wd_bf);
  hipLaunchKernelGGL((gemm_mfma<0>), dim3(64, 12), dim3(256), 0, stream,
                     ekv, wkv_bf, wkv_b, kbuf, vtbuf, nullptr, nullptr);
  hipLaunchKernelGGL(attn_mfma, dim3(kS / 64, kH, kB), dim3(256), 0, stream,
                     qbf, kbuf, vtbuf, pmask, attn_bf);
  hipLaunchKernelGGL((gemm_mfma<1>), dim3(32, 6), dim3(256), 0, stream,
                     attn_bf, wd_bf, dense_b, nullptr, nullptr, out, q_hs);
}